// Round 14
// baseline (1009.881 us; speedup 1.0000x reference)
//
#include <hip/hip_runtime.h>
#include <math.h>
#include <stdint.h>

#define N_NODES 20000
#define M_PAD 20032            // 313 * 64
#define N_EDGES 320000
#define N_GRAPHS 64
#define DIN 128
#define H 256
#define POOL_W 768

typedef __attribute__((ext_vector_type(8))) short bf16x8;   // 8 bf16 = 4 VGPRs
typedef __attribute__((ext_vector_type(4))) float f32x4;

__device__ __forceinline__ unsigned short f2bf(float f) {
    unsigned u = __builtin_bit_cast(unsigned, f);
    u += 0x7FFFu + ((u >> 16) & 1u);          // round-to-nearest-even
    return (unsigned short)(u >> 16);
}
__device__ __forceinline__ float bf2f(unsigned short u) {
    return __builtin_bit_cast(float, (unsigned)u << 16);
}

// ---------------------------------------------------------------------------
// Batched fp32 -> bf16 converts + zero jobs: 9 jobs, one launch.
// Job with s == nullptr writes zeros (d reinterpreted as raw ushort4 span).
// ---------------------------------------------------------------------------
struct CvtJob  { const float* s; unsigned short* d; int n4; };
struct CvtJobs { CvtJob j[9]; };

__global__ __launch_bounds__(256) void cvt_all(CvtJobs jobs)
{
    const CvtJob J = jobs.j[blockIdx.y];
    if (J.s == nullptr) {
        const ushort4 z = {0, 0, 0, 0};
        for (int i = blockIdx.x * 256 + threadIdx.x; i < J.n4; i += gridDim.x * 256)
            ((ushort4*)J.d)[i] = z;
        return;
    }
    for (int i = blockIdx.x * 256 + threadIdx.x; i < J.n4; i += gridDim.x * 256) {
        const float4 v = ((const float4*)J.s)[i];
        ushort4 r;
        r.x = f2bf(v.x); r.y = f2bf(v.y); r.z = f2bf(v.z); r.w = f2bf(v.w);
        ((ushort4*)J.d)[i] = r;
    }
}

// ---------------------------------------------------------------------------
// CSR build
// ---------------------------------------------------------------------------
__global__ __launch_bounds__(256) void hist_kernel(const int* __restrict__ dst,
                                                   int* __restrict__ deg)
{
    const int i = blockIdx.x * 256 + threadIdx.x;
    if (i < N_EDGES) atomicAdd(deg + dst[i], 1);
}

// shfl scan; writes off and cursor; tail threads also compute graph starts
__global__ __launch_bounds__(1024) void scan_kernel(const int* __restrict__ deg,
                                                    int* __restrict__ off,
                                                    int* __restrict__ cur,
                                                    const int* __restrict__ batch,
                                                    int* __restrict__ start)
{
    __shared__ int wsum[16];
    __shared__ int carry;
    const int tid = threadIdx.x, wave = tid >> 6, lane = tid & 63;
    if (tid == 0) carry = 0;
    __syncthreads();
    for (int base = 0; base < N_NODES; base += 1024) {
        const int i = base + tid;
        const int v = (i < N_NODES) ? deg[i] : 0;
        int s = v;
#pragma unroll
        for (int d = 1; d < 64; d <<= 1) {
            const int t = __shfl_up(s, d);
            if (lane >= d) s += t;
        }
        if (lane == 63) wsum[wave] = s;
        __syncthreads();
        if (wave == 0) {
            int t = (lane < 16) ? wsum[lane] : 0;
#pragma unroll
            for (int d = 1; d < 16; d <<= 1) {
                const int u = __shfl_up(t, d);
                if (lane >= d) t += u;
            }
            if (lane < 16) wsum[lane] = t;
        }
        __syncthreads();
        const int wbase = (wave == 0) ? 0 : wsum[wave - 1];
        if (i < N_NODES) {
            const int o = carry + wbase + s - v;
            off[i] = o;
            cur[i] = o;
        }
        const int tot = wsum[15];
        __syncthreads();
        if (tid == 0) carry += tot;
        __syncthreads();
    }
    if (tid == 0) off[N_NODES] = carry;

    // graph boundaries (batch is sorted)
    if (tid <= N_GRAPHS) {
        if (tid == N_GRAPHS) { start[N_GRAPHS] = N_NODES; }
        else {
            int lo = 0, hi = N_NODES;
            while (lo < hi) { const int mid = (lo + hi) >> 1; if (batch[mid] < tid) lo = mid + 1; else hi = mid; }
            start[tid] = lo;
        }
    }
}

// scatter edge payload into dst-sorted order: src id + full 64B ea row
__global__ __launch_bounds__(256) void scatter_kernel(
    const int* __restrict__ src, const int* __restrict__ dst,
    const float4* __restrict__ ea4,
    int* __restrict__ cursor, int* __restrict__ srcS, float4* __restrict__ eaS4)
{
    const int e = blockIdx.x * 256 + threadIdx.x;
    if (e < N_EDGES) {
        const int p = atomicAdd(cursor + dst[e], 1);
        srcS[p] = src[e];
        const float4 a = ea4[e * 4 + 0], b = ea4[e * 4 + 1];
        const float4 c = ea4[e * 4 + 2], d = ea4[e * 4 + 3];
        eaS4[p * 4 + 0] = a; eaS4[p * 4 + 1] = b;
        eaS4[p * 4 + 2] = c; eaS4[p * 4 + 3] = d;
    }
}

// ---------------------------------------------------------------------------
// agg v5 code, launch bounds (256, 8): kernel needs only 44 VGPRs (measured
// R7/R8/R11/R13), which fits the 64-VGPR cap of 8 waves/EU — doubling
// resident waves to hide gather latency with TLP (all per-wave ILP attempts
// spilled: R6/R9/R10). Structure otherwise byte-identical to proven agg5.
// out[v] = bf16( x[v] + sum_e relu(x[src] + ea@We.T + be) )
// ---------------------------------------------------------------------------
template<int IN>
__global__ __launch_bounds__(256, 8) void agg5(
    const unsigned short* __restrict__ xb,   // [M_PAD, IN] bf16
    const float* __restrict__ eaS,           // [E,16] fp32, dst-sorted
    const int* __restrict__ srcS,            // [E] dst-sorted
    const int* __restrict__ off,             // [N+1]
    const float* __restrict__ We, const float* __restrict__ be,
    unsigned short* __restrict__ out)        // [M_PAD, IN] bf16
{
    constexpr int CPL = IN / 64;             // 2 (layer1) or 4
    const int lane = threadIdx.x & 63;
    const int node = blockIdx.x * 4 + (threadIdx.x >> 6);
    if (node >= N_NODES) return;
    const int c0 = lane * CPL;

    float w[CPL][16], bias[CPL], acc[CPL];
#pragma unroll
    for (int j = 0; j < CPL; ++j) {
        bias[j] = be[c0 + j];
        acc[j]  = 0.0f;
#pragma unroll
        for (int k = 0; k < 16; ++k) w[j][k] = We[(c0 + j) * 16 + k];
    }

    const int p0 = __builtin_amdgcn_readfirstlane(off[node]);
    const int p1 = __builtin_amdgcn_readfirstlane(off[node + 1]);

    float  en[16];
    ushort4 xn = {0, 0, 0, 0};
    if (p0 < p1) {
        const int s = __builtin_amdgcn_readfirstlane(srcS[p0]);
        const float* er = eaS + (size_t)p0 * 16;
#pragma unroll
        for (int k = 0; k < 16; ++k) en[k] = er[k];
        if (CPL == 4) xn = *(const ushort4*)(xb + (size_t)s * IN + c0);
        else { const ushort2 t2 = *(const ushort2*)(xb + (size_t)s * IN + c0); xn.x = t2.x; xn.y = t2.y; }
    }

    for (int p = p0; p < p1; ++p) {
        float ec[16];
#pragma unroll
        for (int k = 0; k < 16; ++k) ec[k] = en[k];
        const ushort4 xc = xn;
        if (p + 1 < p1) {
            const int s = __builtin_amdgcn_readfirstlane(srcS[p + 1]);
            const float* er = eaS + (size_t)(p + 1) * 16;
#pragma unroll
            for (int k = 0; k < 16; ++k) en[k] = er[k];
            if (CPL == 4) xn = *(const ushort4*)(xb + (size_t)s * IN + c0);
            else { const ushort2 t2 = *(const ushort2*)(xb + (size_t)s * IN + c0); xn.x = t2.x; xn.y = t2.y; }
        }
        float m[CPL];
#pragma unroll
        for (int j = 0; j < CPL; ++j) m[j] = bias[j];
#pragma unroll
        for (int k = 0; k < 16; ++k)
#pragma unroll
            for (int j = 0; j < CPL; ++j) m[j] = fmaf(ec[k], w[j][k], m[j]);
#pragma unroll
        for (int j = 0; j < CPL; ++j) {
            const float v = m[j] + bf2f((&xc.x)[j]);
            acc[j] += fmaxf(v, 0.0f);
        }
    }

    if (CPL == 4) {
        const ushort4 xs = *(const ushort4*)(xb + (size_t)node * IN + c0);
        ushort4 o;
#pragma unroll
        for (int j = 0; j < 4; ++j) (&o.x)[j] = f2bf(bf2f((&xs.x)[j]) + acc[j]);
        *(ushort4*)(out + (size_t)node * IN + c0) = o;
    } else {
        const ushort2 xs = *(const ushort2*)(xb + (size_t)node * IN + c0);
        ushort2 o;
        o.x = f2bf(bf2f(xs.x) + acc[0]);
        o.y = f2bf(bf2f(xs.y) + acc[1]);
        *(ushort2*)(out + (size_t)node * IN + c0) = o;
    }
}

// ---------------------------------------------------------------------------
// B-in-register streaming GEMM v2 (best measured config, R9):
// grid (313,2), 4 waves/block, wave owns 32 cols with K resident in regs;
// 4 chunks of 16 rows with 2-deep prefetch. No LDS, no barriers.
// EPI 0: BN(eval)+relu -> bf16 (all rows)   EPI 1: bias+relu (rows < N)
// ---------------------------------------------------------------------------
template<int K, int EPI>
__global__ __launch_bounds__(256) void gemm_breg2(
    const unsigned short* __restrict__ A,    // [M_PAD, K]
    const unsigned short* __restrict__ W,    // [256, K]
    const float* __restrict__ bias,
    const float* __restrict__ gsc, const float* __restrict__ bsh,
    unsigned short* __restrict__ out)        // [M_PAD, 256]
{
    constexpr int KC = K / 32;               // 4 or 8 k-chunks
    const int w = threadIdx.x >> 6, lane = threadIdx.x & 63;
    const int lm = lane & 15, lq = lane >> 4;
    const int n0 = (blockIdx.y * 4 + w) * 32;
    const int m0 = blockIdx.x * 64;

    // B resident in registers
    bf16x8 B0[KC], B1[KC];
    {
        const unsigned short* Wp0 = W + (size_t)(n0 + lm) * K + lq * 8;
        const unsigned short* Wp1 = W + (size_t)(n0 + 16 + lm) * K + lq * 8;
#pragma unroll
        for (int c = 0; c < KC; ++c) {
            B0[c] = *(const bf16x8*)(Wp0 + c * 32);
            B1[c] = *(const bf16x8*)(Wp1 + c * 32);
        }
    }

    const float inv = rsqrtf(1.0f + 1e-5f);
    const float bc0 = bias[n0 + lm],      bc1 = bias[n0 + 16 + lm];
    const float gc0 = (EPI == 0) ? gsc[n0 + lm]      : 0.0f;
    const float gc1 = (EPI == 0) ? gsc[n0 + 16 + lm] : 0.0f;
    const float sc0 = (EPI == 0) ? bsh[n0 + lm]      : 0.0f;
    const float sc1 = (EPI == 0) ? bsh[n0 + 16 + lm] : 0.0f;

    bf16x8 aC[KC], aN[KC];
    {
        const unsigned short* Ap = A + (size_t)(m0 + lm) * K + lq * 8;
#pragma unroll
        for (int c = 0; c < KC; ++c) aC[c] = *(const bf16x8*)(Ap + c * 32);
    }

#pragma unroll
    for (int ch = 0; ch < 4; ++ch) {
        if (ch < 3) {
            const unsigned short* Ap = A + (size_t)(m0 + (ch + 1) * 16 + lm) * K + lq * 8;
#pragma unroll
            for (int c = 0; c < KC; ++c) aN[c] = *(const bf16x8*)(Ap + c * 32);
        }

        f32x4 acc0 = (f32x4){0.f, 0.f, 0.f, 0.f};
        f32x4 acc1 = (f32x4){0.f, 0.f, 0.f, 0.f};
#pragma unroll
        for (int c = 0; c < KC; ++c) {
            acc0 = __builtin_amdgcn_mfma_f32_16x16x32_bf16(aC[c], B0[c], acc0, 0, 0, 0);
            acc1 = __builtin_amdgcn_mfma_f32_16x16x32_bf16(aC[c], B1[c], acc1, 0, 0, 0);
        }

        const int mr = m0 + ch * 16;
#pragma unroll
        for (int r = 0; r < 4; ++r) {
            const int row = mr + lq * 4 + r;
            if (EPI == 1 && row >= N_NODES) continue;
            float v0 = acc0[r] + bc0;
            float v1 = acc1[r] + bc1;
            if (EPI == 0) {
                v0 = fmaxf(v0 * inv * gc0 + sc0, 0.0f);
                v1 = fmaxf(v1 * inv * gc1 + sc1, 0.0f);
            } else {
                v0 = fmaxf(v0, 0.0f);
                v1 = fmaxf(v1, 0.0f);
            }
            out[(size_t)row * H + n0 + lm]      = f2bf(v0);
            out[(size_t)row * H + n0 + 16 + lm] = f2bf(v1);
        }

#pragma unroll
        for (int c = 0; c < KC; ++c) aC[c] = aN[c];
    }
}

// ---------------------------------------------------------------------------
// Parallel mean-pool: grid (192, RSPLIT). Block (g, layer, chunk) reduces
// ~rows/RSPLIT rows and atomicAdds one partial per column into pool.
// ---------------------------------------------------------------------------
#define RSPLIT 6
__global__ __launch_bounds__(256) void pool2(
    const unsigned short* __restrict__ h1, const unsigned short* __restrict__ h2,
    const unsigned short* __restrict__ h3, const int* __restrict__ start,
    float* __restrict__ pool)
{
    const int g = blockIdx.x & 63, layer = blockIdx.x >> 6;
    const unsigned short* h = (layer == 0) ? h1 : (layer == 1) ? h2 : h3;
    const int r0 = start[g], r1 = start[g + 1];
    const int nr = r1 - r0;
    if (nr <= 0) return;
    const int chunk = (nr + RSPLIT - 1) / RSPLIT;
    const int rs = r0 + blockIdx.y * chunk;
    const int re = (rs + chunk < r1) ? rs + chunk : r1;
    if (rs >= re) return;

    const int c = threadIdx.x;
    float s0 = 0.f, s1 = 0.f, s2 = 0.f, s3 = 0.f;
    int r = rs;
    for (; r + 4 <= re; r += 4) {
        s0 += bf2f(h[(size_t)(r + 0) * H + c]);
        s1 += bf2f(h[(size_t)(r + 1) * H + c]);
        s2 += bf2f(h[(size_t)(r + 2) * H + c]);
        s3 += bf2f(h[(size_t)(r + 3) * H + c]);
    }
    for (; r < re; ++r) s0 += bf2f(h[(size_t)r * H + c]);
    atomicAdd(&pool[(size_t)g * POOL_W + layer * 256 + c], s0 + s1 + s2 + s3);
}

// ---------------------------------------------------------------------------
// FC head: one block per graph; pool is pre-summed (divide by count here).
// ---------------------------------------------------------------------------
__global__ __launch_bounds__(256) void final_kernel(
    const float* __restrict__ pool, const int* __restrict__ start,
    const float* __restrict__ L1w, const float* __restrict__ L1b,
    const float* __restrict__ L2w, const float* __restrict__ L2b,
    float* __restrict__ out)
{
    const int g = blockIdx.x;
    __shared__ float p[POOL_W];
    __shared__ float f1[POOL_W];
    __shared__ float red[4];

    const float rc = 1.0f / fmaxf((float)(start[g + 1] - start[g]), 1.0f);
    for (int i = threadIdx.x; i < POOL_W; i += 256)
        p[i] = pool[(size_t)g * POOL_W + i] * rc;
    __syncthreads();

    for (int r = 0; r < 3; ++r) {
        const int o = r * 256 + threadIdx.x;
        float acc = L1b[o];
        const float4* wrow = (const float4*)(L1w + (size_t)o * POOL_W);
        for (int k4 = 0; k4 < POOL_W / 4; ++k4) {
            const float4 w4 = wrow[k4];
            acc += w4.x * p[k4 * 4 + 0] + w4.y * p[k4 * 4 + 1]
                 + w4.z * p[k4 * 4 + 2] + w4.w * p[k4 * 4 + 3];
        }
        f1[o] = fmaxf(acc, 0.0f);
    }
    __syncthreads();

    float part = 0.0f;
    for (int i = threadIdx.x; i < POOL_W; i += 256) part += f1[i] * L2w[i];
#pragma unroll
    for (int off = 32; off > 0; off >>= 1) part += __shfl_down(part, off);
    if ((threadIdx.x & 63) == 0) red[threadIdx.x >> 6] = part;
    __syncthreads();
    if (threadIdx.x == 0) {
        const float s = red[0] + red[1] + red[2] + red[3] + L2b[0];
        out[g] = 1.0f / (1.0f + expf(-s));
    }
}

// ---------------------------------------------------------------------------
extern "C" void kernel_launch(void* const* d_in, const int* in_sizes, int n_in,
                              void* d_out, int out_size, void* d_ws, size_t ws_size,
                              hipStream_t stream)
{
    const float* x     = (const float*)d_in[0];
    const float* ea    = (const float*)d_in[1];
    const int*   src   = (const int*)d_in[2];
    const int*   dst   = (const int*)d_in[3];
    const int*   batch = (const int*)d_in[4];

    const float* We[3]; const float* be[3]; const float* Wa[3]; const float* ba[3];
    const float* gg[3]; const float* bt[3]; const float* Wb[3]; const float* bb[3];
    for (int l = 0; l < 3; ++l) {
        const int o = 5 + 8 * l;
        We[l] = (const float*)d_in[o + 0]; be[l] = (const float*)d_in[o + 1];
        Wa[l] = (const float*)d_in[o + 2]; ba[l] = (const float*)d_in[o + 3];
        gg[l] = (const float*)d_in[o + 4]; bt[l] = (const float*)d_in[o + 5];
        Wb[l] = (const float*)d_in[o + 6]; bb[l] = (const float*)d_in[o + 7];
    }
    const float* L1w = (const float*)d_in[29];
    const float* L1b = (const float*)d_in[30];
    const float* L2w = (const float*)d_in[31];
    const float* L2b = (const float*)d_in[32];

    // ---- workspace layout ----
    float* pool   = (float*)d_ws;                              // 64*768
    int*   deg    = (int*)(pool + (size_t)N_GRAPHS * POOL_W);  // N
    int*   off    = deg + N_NODES;                             // N+1
    int*   cursor = off + N_NODES + 1;                         // N
    int*   start  = cursor + N_NODES;                          // 72
    int*   srcS   = start + 72;                                // E
    float* eaS    = (float*)((((uintptr_t)(srcS + N_EDGES)) + 63) & ~(uintptr_t)63);  // E*16
    unsigned short* xb = (unsigned short*)(eaS + (size_t)N_EDGES * 16);
    unsigned short* u  = xb + (size_t)M_PAD * DIN;             // [M_PAD,256] (layer1 uses 128)
    unsigned short* tT = u  + (size_t)M_PAD * H;               // [M_PAD,256] intermediate
    unsigned short* h1 = tT + (size_t)M_PAD * H;
    unsigned short* h2 = h1 + (size_t)M_PAD * H;
    unsigned short* h3 = h2 + (size_t)M_PAD * H;
    unsigned short* wbf[6];
    wbf[0] = h3 + (size_t)M_PAD * H;                           // Wa1 [256,128]
    wbf[1] = wbf[0] + H * DIN;
    for (int i = 2; i < 6; ++i) wbf[i] = wbf[i - 1] + H * H;

    // batched converts + deg/pool zeroing in one launch (9 jobs)
    CvtJobs jobs;
    jobs.j[0] = { x,       xb,                    N_NODES * DIN / 4 };
    jobs.j[1] = { Wa[0],   wbf[0],                H * DIN / 4 };
    jobs.j[2] = { Wb[0],   wbf[1],                H * H / 4 };
    jobs.j[3] = { Wa[1],   wbf[2],                H * H / 4 };
    jobs.j[4] = { Wb[1],   wbf[3],                H * H / 4 };
    jobs.j[5] = { Wa[2],   wbf[4],                H * H / 4 };
    jobs.j[6] = { Wb[2],   wbf[5],                H * H / 4 };
    jobs.j[7] = { nullptr, (unsigned short*)deg,  N_NODES * 4 / 8 };           // zero N ints
    jobs.j[8] = { nullptr, (unsigned short*)pool, N_GRAPHS * POOL_W * 4 / 8 }; // zero pool
    cvt_all<<<dim3(320, 9), 256, 0, stream>>>(jobs);

    // CSR + graph boundaries
    hist_kernel<<<(N_EDGES + 255) / 256, 256, 0, stream>>>(dst, deg);
    scan_kernel<<<1, 1024, 0, stream>>>(deg, off, cursor, batch, start);
    scatter_kernel<<<(N_EDGES + 255) / 256, 256, 0, stream>>>(src, dst, (const float4*)ea,
                                                              cursor, srcS, (float4*)eaS);

    const int  agrid = (N_NODES + 3) / 4;       // agg5: 1 node/wave
    const dim3 ggrid(M_PAD / 64, 2);            // (313, 2)

    // ---- layer 1 (in=128) ----
    agg5<DIN><<<agrid, 256, 0, stream>>>(xb, eaS, srcS, off, We[0], be[0], u);
    gemm_breg2<DIN, 0><<<ggrid, 256, 0, stream>>>(u, wbf[0], ba[0], gg[0], bt[0], tT);
    gemm_breg2<H,   1><<<ggrid, 256, 0, stream>>>(tT, wbf[1], bb[0], nullptr, nullptr, h1);
    // ---- layer 2 ----
    agg5<H><<<agrid, 256, 0, stream>>>(h1, eaS, srcS, off, We[1], be[1], u);
    gemm_breg2<H, 0><<<ggrid, 256, 0, stream>>>(u, wbf[2], ba[1], gg[1], bt[1], tT);
    gemm_breg2<H, 1><<<ggrid, 256, 0, stream>>>(tT, wbf[3], bb[1], nullptr, nullptr, h2);
    // ---- layer 3 ----
    agg5<H><<<agrid, 256, 0, stream>>>(h2, eaS, srcS, off, We[2], be[2], u);
    gemm_breg2<H, 0><<<ggrid, 256, 0, stream>>>(u, wbf[4], ba[2], gg[2], bt[2], tT);
    gemm_breg2<H, 1><<<ggrid, 256, 0, stream>>>(tT, wbf[5], bb[2], nullptr, nullptr, h3);

    // parallel mean-pool + head
    pool2<<<dim3(3 * N_GRAPHS, RSPLIT), 256, 0, stream>>>(h1, h2, h3, start, pool);
    final_kernel<<<N_GRAPHS, 256, 0, stream>>>(pool, start, L1w, L1b, L2w, L2b, (float*)d_out);
}

// Round 15
// 607.635 us; speedup vs baseline: 1.6620x; 1.6620x over previous
//
#include <hip/hip_runtime.h>
#include <math.h>
#include <stdint.h>

#define N_NODES 20000
#define M_PAD 20032            // 313 * 64
#define N_EDGES 320000
#define N_GRAPHS 64
#define DIN 128
#define H 256
#define POOL_W 768

typedef __attribute__((ext_vector_type(8))) short bf16x8;   // 8 bf16 = 4 VGPRs
typedef __attribute__((ext_vector_type(4))) float f32x4;

__device__ __forceinline__ unsigned short f2bf(float f) {
    unsigned u = __builtin_bit_cast(unsigned, f);
    u += 0x7FFFu + ((u >> 16) & 1u);          // round-to-nearest-even
    return (unsigned short)(u >> 16);
}
__device__ __forceinline__ float bf2f(unsigned short u) {
    return __builtin_bit_cast(float, (unsigned)u << 16);
}

// ---------------------------------------------------------------------------
// Batched fp32 -> bf16 converts + zero jobs: 9 jobs, one launch.
// Job with s == nullptr writes zeros (d reinterpreted as raw ushort4 span).
// ---------------------------------------------------------------------------
struct CvtJob  { const float* s; unsigned short* d; int n4; };
struct CvtJobs { CvtJob j[9]; };

__global__ __launch_bounds__(256) void cvt_all(CvtJobs jobs)
{
    const CvtJob J = jobs.j[blockIdx.y];
    if (J.s == nullptr) {
        const ushort4 z = {0, 0, 0, 0};
        for (int i = blockIdx.x * 256 + threadIdx.x; i < J.n4; i += gridDim.x * 256)
            ((ushort4*)J.d)[i] = z;
        return;
    }
    for (int i = blockIdx.x * 256 + threadIdx.x; i < J.n4; i += gridDim.x * 256) {
        const float4 v = ((const float4*)J.s)[i];
        ushort4 r;
        r.x = f2bf(v.x); r.y = f2bf(v.y); r.z = f2bf(v.z); r.w = f2bf(v.w);
        ((ushort4*)J.d)[i] = r;
    }
}

// ---------------------------------------------------------------------------
// CSR build
// ---------------------------------------------------------------------------
__global__ __launch_bounds__(256) void hist_kernel(const int* __restrict__ dst,
                                                   int* __restrict__ deg)
{
    const int i = blockIdx.x * 256 + threadIdx.x;
    if (i < N_EDGES) atomicAdd(deg + dst[i], 1);
}

// shfl scan; writes off and cursor; tail threads also compute graph starts
__global__ __launch_bounds__(1024) void scan_kernel(const int* __restrict__ deg,
                                                    int* __restrict__ off,
                                                    int* __restrict__ cur,
                                                    const int* __restrict__ batch,
                                                    int* __restrict__ start)
{
    __shared__ int wsum[16];
    __shared__ int carry;
    const int tid = threadIdx.x, wave = tid >> 6, lane = tid & 63;
    if (tid == 0) carry = 0;
    __syncthreads();
    for (int base = 0; base < N_NODES; base += 1024) {
        const int i = base + tid;
        const int v = (i < N_NODES) ? deg[i] : 0;
        int s = v;
#pragma unroll
        for (int d = 1; d < 64; d <<= 1) {
            const int t = __shfl_up(s, d);
            if (lane >= d) s += t;
        }
        if (lane == 63) wsum[wave] = s;
        __syncthreads();
        if (wave == 0) {
            int t = (lane < 16) ? wsum[lane] : 0;
#pragma unroll
            for (int d = 1; d < 16; d <<= 1) {
                const int u = __shfl_up(t, d);
                if (lane >= d) t += u;
            }
            if (lane < 16) wsum[lane] = t;
        }
        __syncthreads();
        const int wbase = (wave == 0) ? 0 : wsum[wave - 1];
        if (i < N_NODES) {
            const int o = carry + wbase + s - v;
            off[i] = o;
            cur[i] = o;
        }
        const int tot = wsum[15];
        __syncthreads();
        if (tid == 0) carry += tot;
        __syncthreads();
    }
    if (tid == 0) off[N_NODES] = carry;

    // graph boundaries (batch is sorted)
    if (tid <= N_GRAPHS) {
        if (tid == N_GRAPHS) { start[N_GRAPHS] = N_NODES; }
        else {
            int lo = 0, hi = N_NODES;
            while (lo < hi) { const int mid = (lo + hi) >> 1; if (batch[mid] < tid) lo = mid + 1; else hi = mid; }
            start[tid] = lo;
        }
    }
}

// light scatter (R5 config): dst-sorted (src, eid) pairs only — 2.5 MB
__global__ __launch_bounds__(256) void scatter_kernel(
    const int* __restrict__ src, const int* __restrict__ dst,
    int* __restrict__ cursor, int2* __restrict__ sidx)
{
    const int e = blockIdx.x * 256 + threadIdx.x;
    if (e < N_EDGES) {
        const int p = atomicAdd(cursor + dst[e], 1);
        sidx[p] = make_int2(src[e], e);
    }
}

// ---------------------------------------------------------------------------
// agg3 (R5's measured-best variant: 93.4-95.1 us, VGPR 44 — DO NOT PERTURB;
// R6/R9/R10/R14 all regressed under structural or launch-bounds changes).
// One wave per node, CPL ch/lane, 1-deep pipeline; (src,eid) via one 8B
// scalar load, ea row via SGPR scalar loads (wave-uniform address).
// out[v] = bf16( x[v] + sum_e relu(x[src] + ea@We.T + be) )
// ---------------------------------------------------------------------------
template<int IN>
__global__ __launch_bounds__(256, 4) void agg3(
    const unsigned short* __restrict__ xb,   // [M_PAD, IN] bf16
    const float* __restrict__ ea,            // [E,16] fp32 (original order)
    const int2* __restrict__ sidx,           // (src, eid) sorted by dst
    const int* __restrict__ off,             // [N+1]
    const float* __restrict__ We, const float* __restrict__ be,
    unsigned short* __restrict__ out)        // [M_PAD, IN] bf16
{
    constexpr int CPL = IN / 64;             // 2 (layer1) or 4
    const int lane = threadIdx.x & 63;
    const int node = blockIdx.x * 4 + (threadIdx.x >> 6);
    if (node >= N_NODES) return;
    const int c0 = lane * CPL;

    float w[CPL][16], bias[CPL], acc[CPL];
#pragma unroll
    for (int j = 0; j < CPL; ++j) {
        bias[j] = be[c0 + j];
        acc[j]  = 0.0f;
#pragma unroll
        for (int k = 0; k < 16; ++k) w[j][k] = We[(c0 + j) * 16 + k];
    }

    const int p0 = __builtin_amdgcn_readfirstlane(off[node]);
    const int p1 = __builtin_amdgcn_readfirstlane(off[node + 1]);

    float  en[16];
    ushort4 xn = {0, 0, 0, 0};
    if (p0 < p1) {
        const int2 se = sidx[p0];
        const int s = __builtin_amdgcn_readfirstlane(se.x);
        const int e = __builtin_amdgcn_readfirstlane(se.y);
        const float* er = ea + (size_t)e * 16;
#pragma unroll
        for (int k = 0; k < 16; ++k) en[k] = er[k];
        if (CPL == 4) xn = *(const ushort4*)(xb + (size_t)s * IN + c0);
        else { const ushort2 t2 = *(const ushort2*)(xb + (size_t)s * IN + c0); xn.x = t2.x; xn.y = t2.y; }
    }

    for (int p = p0; p < p1; ++p) {
        float ec[16];
#pragma unroll
        for (int k = 0; k < 16; ++k) ec[k] = en[k];
        const ushort4 xc = xn;
        if (p + 1 < p1) {
            const int2 se = sidx[p + 1];
            const int s = __builtin_amdgcn_readfirstlane(se.x);
            const int e = __builtin_amdgcn_readfirstlane(se.y);
            const float* er = ea + (size_t)e * 16;
#pragma unroll
            for (int k = 0; k < 16; ++k) en[k] = er[k];
            if (CPL == 4) xn = *(const ushort4*)(xb + (size_t)s * IN + c0);
            else { const ushort2 t2 = *(const ushort2*)(xb + (size_t)s * IN + c0); xn.x = t2.x; xn.y = t2.y; }
        }
        float m[CPL];
#pragma unroll
        for (int j = 0; j < CPL; ++j) m[j] = bias[j];
#pragma unroll
        for (int k = 0; k < 16; ++k)
#pragma unroll
            for (int j = 0; j < CPL; ++j) m[j] = fmaf(ec[k], w[j][k], m[j]);
#pragma unroll
        for (int j = 0; j < CPL; ++j) {
            const float v = m[j] + bf2f((&xc.x)[j]);
            acc[j] += fmaxf(v, 0.0f);
        }
    }

    if (CPL == 4) {
        const ushort4 xs = *(const ushort4*)(xb + (size_t)node * IN + c0);
        ushort4 o;
#pragma unroll
        for (int j = 0; j < 4; ++j) (&o.x)[j] = f2bf(bf2f((&xs.x)[j]) + acc[j]);
        *(ushort4*)(out + (size_t)node * IN + c0) = o;
    } else {
        const ushort2 xs = *(const ushort2*)(xb + (size_t)node * IN + c0);
        ushort2 o;
        o.x = f2bf(bf2f(xs.x) + acc[0]);
        o.y = f2bf(bf2f(xs.y) + acc[1]);
        *(ushort2*)(out + (size_t)node * IN + c0) = o;
    }
}

// ---------------------------------------------------------------------------
// B-in-register streaming GEMM v2 (best measured config, R9):
// grid (313,2), 4 waves/block, wave owns 32 cols with K resident in regs;
// 4 chunks of 16 rows with 2-deep prefetch. No LDS, no barriers.
// EPI 0: BN(eval)+relu -> bf16 (all rows)   EPI 1: bias+relu (rows < N)
// ---------------------------------------------------------------------------
template<int K, int EPI>
__global__ __launch_bounds__(256) void gemm_breg2(
    const unsigned short* __restrict__ A,    // [M_PAD, K]
    const unsigned short* __restrict__ W,    // [256, K]
    const float* __restrict__ bias,
    const float* __restrict__ gsc, const float* __restrict__ bsh,
    unsigned short* __restrict__ out)        // [M_PAD, 256]
{
    constexpr int KC = K / 32;               // 4 or 8 k-chunks
    const int w = threadIdx.x >> 6, lane = threadIdx.x & 63;
    const int lm = lane & 15, lq = lane >> 4;
    const int n0 = (blockIdx.y * 4 + w) * 32;
    const int m0 = blockIdx.x * 64;

    // B resident in registers
    bf16x8 B0[KC], B1[KC];
    {
        const unsigned short* Wp0 = W + (size_t)(n0 + lm) * K + lq * 8;
        const unsigned short* Wp1 = W + (size_t)(n0 + 16 + lm) * K + lq * 8;
#pragma unroll
        for (int c = 0; c < KC; ++c) {
            B0[c] = *(const bf16x8*)(Wp0 + c * 32);
            B1[c] = *(const bf16x8*)(Wp1 + c * 32);
        }
    }

    const float inv = rsqrtf(1.0f + 1e-5f);
    const float bc0 = bias[n0 + lm],      bc1 = bias[n0 + 16 + lm];
    const float gc0 = (EPI == 0) ? gsc[n0 + lm]      : 0.0f;
    const float gc1 = (EPI == 0) ? gsc[n0 + 16 + lm] : 0.0f;
    const float sc0 = (EPI == 0) ? bsh[n0 + lm]      : 0.0f;
    const float sc1 = (EPI == 0) ? bsh[n0 + 16 + lm] : 0.0f;

    bf16x8 aC[KC], aN[KC];
    {
        const unsigned short* Ap = A + (size_t)(m0 + lm) * K + lq * 8;
#pragma unroll
        for (int c = 0; c < KC; ++c) aC[c] = *(const bf16x8*)(Ap + c * 32);
    }

#pragma unroll
    for (int ch = 0; ch < 4; ++ch) {
        if (ch < 3) {
            const unsigned short* Ap = A + (size_t)(m0 + (ch + 1) * 16 + lm) * K + lq * 8;
#pragma unroll
            for (int c = 0; c < KC; ++c) aN[c] = *(const bf16x8*)(Ap + c * 32);
        }

        f32x4 acc0 = (f32x4){0.f, 0.f, 0.f, 0.f};
        f32x4 acc1 = (f32x4){0.f, 0.f, 0.f, 0.f};
#pragma unroll
        for (int c = 0; c < KC; ++c) {
            acc0 = __builtin_amdgcn_mfma_f32_16x16x32_bf16(aC[c], B0[c], acc0, 0, 0, 0);
            acc1 = __builtin_amdgcn_mfma_f32_16x16x32_bf16(aC[c], B1[c], acc1, 0, 0, 0);
        }

        const int mr = m0 + ch * 16;
#pragma unroll
        for (int r = 0; r < 4; ++r) {
            const int row = mr + lq * 4 + r;
            if (EPI == 1 && row >= N_NODES) continue;
            float v0 = acc0[r] + bc0;
            float v1 = acc1[r] + bc1;
            if (EPI == 0) {
                v0 = fmaxf(v0 * inv * gc0 + sc0, 0.0f);
                v1 = fmaxf(v1 * inv * gc1 + sc1, 0.0f);
            } else {
                v0 = fmaxf(v0, 0.0f);
                v1 = fmaxf(v1, 0.0f);
            }
            out[(size_t)row * H + n0 + lm]      = f2bf(v0);
            out[(size_t)row * H + n0 + 16 + lm] = f2bf(v1);
        }

#pragma unroll
        for (int c = 0; c < KC; ++c) aC[c] = aN[c];
    }
}

// ---------------------------------------------------------------------------
// Parallel mean-pool: grid (192, RSPLIT). Block (g, layer, chunk) reduces
// ~rows/RSPLIT rows and atomicAdds one partial per column into pool.
// ---------------------------------------------------------------------------
#define RSPLIT 6
__global__ __launch_bounds__(256) void pool2(
    const unsigned short* __restrict__ h1, const unsigned short* __restrict__ h2,
    const unsigned short* __restrict__ h3, const int* __restrict__ start,
    float* __restrict__ pool)
{
    const int g = blockIdx.x & 63, layer = blockIdx.x >> 6;
    const unsigned short* h = (layer == 0) ? h1 : (layer == 1) ? h2 : h3;
    const int r0 = start[g], r1 = start[g + 1];
    const int nr = r1 - r0;
    if (nr <= 0) return;
    const int chunk = (nr + RSPLIT - 1) / RSPLIT;
    const int rs = r0 + blockIdx.y * chunk;
    const int re = (rs + chunk < r1) ? rs + chunk : r1;
    if (rs >= re) return;

    const int c = threadIdx.x;
    float s0 = 0.f, s1 = 0.f, s2 = 0.f, s3 = 0.f;
    int r = rs;
    for (; r + 4 <= re; r += 4) {
        s0 += bf2f(h[(size_t)(r + 0) * H + c]);
        s1 += bf2f(h[(size_t)(r + 1) * H + c]);
        s2 += bf2f(h[(size_t)(r + 2) * H + c]);
        s3 += bf2f(h[(size_t)(r + 3) * H + c]);
    }
    for (; r < re; ++r) s0 += bf2f(h[(size_t)r * H + c]);
    atomicAdd(&pool[(size_t)g * POOL_W + layer * 256 + c], s0 + s1 + s2 + s3);
}

// ---------------------------------------------------------------------------
// FC head: one block per graph; pool is pre-summed (divide by count here).
// ---------------------------------------------------------------------------
__global__ __launch_bounds__(256) void final_kernel(
    const float* __restrict__ pool, const int* __restrict__ start,
    const float* __restrict__ L1w, const float* __restrict__ L1b,
    const float* __restrict__ L2w, const float* __restrict__ L2b,
    float* __restrict__ out)
{
    const int g = blockIdx.x;
    __shared__ float p[POOL_W];
    __shared__ float f1[POOL_W];
    __shared__ float red[4];

    const float rc = 1.0f / fmaxf((float)(start[g + 1] - start[g]), 1.0f);
    for (int i = threadIdx.x; i < POOL_W; i += 256)
        p[i] = pool[(size_t)g * POOL_W + i] * rc;
    __syncthreads();

    for (int r = 0; r < 3; ++r) {
        const int o = r * 256 + threadIdx.x;
        float acc = L1b[o];
        const float4* wrow = (const float4*)(L1w + (size_t)o * POOL_W);
        for (int k4 = 0; k4 < POOL_W / 4; ++k4) {
            const float4 w4 = wrow[k4];
            acc += w4.x * p[k4 * 4 + 0] + w4.y * p[k4 * 4 + 1]
                 + w4.z * p[k4 * 4 + 2] + w4.w * p[k4 * 4 + 3];
        }
        f1[o] = fmaxf(acc, 0.0f);
    }
    __syncthreads();

    float part = 0.0f;
    for (int i = threadIdx.x; i < POOL_W; i += 256) part += f1[i] * L2w[i];
#pragma unroll
    for (int off = 32; off > 0; off >>= 1) part += __shfl_down(part, off);
    if ((threadIdx.x & 63) == 0) red[threadIdx.x >> 6] = part;
    __syncthreads();
    if (threadIdx.x == 0) {
        const float s = red[0] + red[1] + red[2] + red[3] + L2b[0];
        out[g] = 1.0f / (1.0f + expf(-s));
    }
}

// ---------------------------------------------------------------------------
extern "C" void kernel_launch(void* const* d_in, const int* in_sizes, int n_in,
                              void* d_out, int out_size, void* d_ws, size_t ws_size,
                              hipStream_t stream)
{
    const float* x     = (const float*)d_in[0];
    const float* ea    = (const float*)d_in[1];
    const int*   src   = (const int*)d_in[2];
    const int*   dst   = (const int*)d_in[3];
    const int*   batch = (const int*)d_in[4];

    const float* We[3]; const float* be[3]; const float* Wa[3]; const float* ba[3];
    const float* gg[3]; const float* bt[3]; const float* Wb[3]; const float* bb[3];
    for (int l = 0; l < 3; ++l) {
        const int o = 5 + 8 * l;
        We[l] = (const float*)d_in[o + 0]; be[l] = (const float*)d_in[o + 1];
        Wa[l] = (const float*)d_in[o + 2]; ba[l] = (const float*)d_in[o + 3];
        gg[l] = (const float*)d_in[o + 4]; bt[l] = (const float*)d_in[o + 5];
        Wb[l] = (const float*)d_in[o + 6]; bb[l] = (const float*)d_in[o + 7];
    }
    const float* L1w = (const float*)d_in[29];
    const float* L1b = (const float*)d_in[30];
    const float* L2w = (const float*)d_in[31];
    const float* L2b = (const float*)d_in[32];

    // ---- workspace layout ----
    float* pool   = (float*)d_ws;                              // 64*768
    int*   deg    = (int*)(pool + (size_t)N_GRAPHS * POOL_W);  // N
    int*   off    = deg + N_NODES;                             // N+1
    int*   cursor = off + N_NODES + 1;                         // N
    int*   start  = cursor + N_NODES;                          // 72
    int2*  sidx   = (int2*)((((uintptr_t)(start + 72)) + 15) & ~(uintptr_t)15);  // E
    unsigned short* xb = (unsigned short*)((((uintptr_t)(sidx + N_EDGES)) + 15) & ~(uintptr_t)15);
    unsigned short* u  = xb + (size_t)M_PAD * DIN;             // [M_PAD,256] (layer1 uses 128)
    unsigned short* tT = u  + (size_t)M_PAD * H;               // [M_PAD,256] intermediate
    unsigned short* h1 = tT + (size_t)M_PAD * H;
    unsigned short* h2 = h1 + (size_t)M_PAD * H;
    unsigned short* h3 = h2 + (size_t)M_PAD * H;
    unsigned short* wbf[6];
    wbf[0] = h3 + (size_t)M_PAD * H;                           // Wa1 [256,128]
    wbf[1] = wbf[0] + H * DIN;
    for (int i = 2; i < 6; ++i) wbf[i] = wbf[i - 1] + H * H;

    // batched converts + deg/pool zeroing in one launch (9 jobs)
    CvtJobs jobs;
    jobs.j[0] = { x,       xb,                    N_NODES * DIN / 4 };
    jobs.j[1] = { Wa[0],   wbf[0],                H * DIN / 4 };
    jobs.j[2] = { Wb[0],   wbf[1],                H * H / 4 };
    jobs.j[3] = { Wa[1],   wbf[2],                H * H / 4 };
    jobs.j[4] = { Wb[1],   wbf[3],                H * H / 4 };
    jobs.j[5] = { Wa[2],   wbf[4],                H * H / 4 };
    jobs.j[6] = { Wb[2],   wbf[5],                H * H / 4 };
    jobs.j[7] = { nullptr, (unsigned short*)deg,  N_NODES * 4 / 8 };           // zero N ints
    jobs.j[8] = { nullptr, (unsigned short*)pool, N_GRAPHS * POOL_W * 4 / 8 }; // zero pool
    cvt_all<<<dim3(320, 9), 256, 0, stream>>>(jobs);

    // CSR + graph boundaries
    hist_kernel<<<(N_EDGES + 255) / 256, 256, 0, stream>>>(dst, deg);
    scan_kernel<<<1, 1024, 0, stream>>>(deg, off, cursor, batch, start);
    scatter_kernel<<<(N_EDGES + 255) / 256, 256, 0, stream>>>(src, dst, cursor, sidx);

    const int  agrid = (N_NODES + 3) / 4;       // agg3: 1 node/wave
    const dim3 ggrid(M_PAD / 64, 2);            // (313, 2)

    // ---- layer 1 (in=128) ----
    agg3<DIN><<<agrid, 256, 0, stream>>>(xb, ea, sidx, off, We[0], be[0], u);
    gemm_breg2<DIN, 0><<<ggrid, 256, 0, stream>>>(u, wbf[0], ba[0], gg[0], bt[0], tT);
    gemm_breg2<H,   1><<<ggrid, 256, 0, stream>>>(tT, wbf[1], bb[0], nullptr, nullptr, h1);
    // ---- layer 2 ----
    agg3<H><<<agrid, 256, 0, stream>>>(h1, ea, sidx, off, We[1], be[1], u);
    gemm_breg2<H, 0><<<ggrid, 256, 0, stream>>>(u, wbf[2], ba[1], gg[1], bt[1], tT);
    gemm_breg2<H, 1><<<ggrid, 256, 0, stream>>>(tT, wbf[3], bb[1], nullptr, nullptr, h2);
    // ---- layer 3 ----
    agg3<H><<<agrid, 256, 0, stream>>>(h2, ea, sidx, off, We[2], be[2], u);
    gemm_breg2<H, 0><<<ggrid, 256, 0, stream>>>(u, wbf[4], ba[2], gg[2], bt[2], tT);
    gemm_breg2<H, 1><<<ggrid, 256, 0, stream>>>(tT, wbf[5], bb[2], nullptr, nullptr, h3);

    // parallel mean-pool + head
    pool2<<<dim3(3 * N_GRAPHS, RSPLIT), 256, 0, stream>>>(h1, h2, h3, start, pool);
    final_kernel<<<N_GRAPHS, 256, 0, stream>>>(pool, start, L1w, L1b, L2w, L2b, (float*)d_out);
}